// Round 1
// baseline (5508.728 us; speedup 1.0000x reference)
//
#include <hip/hip_runtime.h>

#define NN 100000
#define EE 1600000
#define DD 128

// ---------------------------------------------------------------------------
// SpMM: out[dst] += val * H[src]   (edge-parallel, 32 lanes per edge, float4)
// ---------------------------------------------------------------------------
__global__ __launch_bounds__(256) void spmm_atomic(
    const float* __restrict__ H, const int* __restrict__ src,
    const int* __restrict__ dst, const float* __restrict__ val,
    float* __restrict__ out, int E)
{
    int t = blockIdx.x * 256 + threadIdx.x;
    int e = t >> 5;
    if (e >= E) return;
    int l = t & 31;
    int s = src[e];
    int d = dst[e];
    float v = val[e];
    const float4 h4 = *reinterpret_cast<const float4*>(&H[(size_t)s * DD + l * 4]);
    float* o = &out[(size_t)d * DD + l * 4];
    atomicAdd(o + 0, v * h4.x);
    atomicAdd(o + 1, v * h4.y);
    atomicAdd(o + 2, v * h4.z);
    atomicAdd(o + 3, v * h4.w);
}

// ---------------------------------------------------------------------------
// O = relu(H @ W + b)   H:[n][128]  W:[128][128]  b:[128]
// block: 256 threads, 128 rows x 128 cols; per-thread 8x8 register tile.
// k-chunked (32) LDS staging; H tile XOR-swizzled for conflict-free reads.
// ---------------------------------------------------------------------------
__global__ __launch_bounds__(256) void linear_relu(
    const float* __restrict__ H, const float* __restrict__ W,
    const float* __restrict__ bias, float* __restrict__ O, int n)
{
    __shared__ float WS[32 * 128];   // [kk][c]
    __shared__ float HS[128 * 32];   // [r][kk], float4 slots swizzled by row-group
    const int t  = threadIdx.x;
    const int tx = t & 15;           // col group: cols {4tx..4tx+3, 64+4tx..}
    const int ty = t >> 4;           // row group: rows ty*8..ty*8+7
    const int row0 = blockIdx.x * 128;
    const int c0 = tx * 4;
    const int c1 = 64 + tx * 4;

    float acc0[8][4];
    float acc1[8][4];
#pragma unroll
    for (int i = 0; i < 8; ++i)
#pragma unroll
        for (int j = 0; j < 4; ++j) { acc0[i][j] = 0.f; acc1[i][j] = 0.f; }

    for (int kc = 0; kc < 4; ++kc) {
        __syncthreads();
        // stage W chunk [32][128]
#pragma unroll
        for (int g = 0; g < 4; ++g) {
            int idx = t + g * 256;        // 1024 float4s
            int kk  = idx >> 5;
            int c4  = (idx & 31) * 4;
            *reinterpret_cast<float4*>(&WS[kk * 128 + c4]) =
                *reinterpret_cast<const float4*>(&W[(size_t)(kc * 32 + kk) * 128 + c4]);
        }
        // stage H chunk [128][32], swizzled: slot = r*8 + (q ^ ((r>>3)&3))
#pragma unroll
        for (int g = 0; g < 4; ++g) {
            int idx = t + g * 256;
            int r = idx >> 3;
            int q = idx & 7;
            float4 hv = make_float4(0.f, 0.f, 0.f, 0.f);
            int row = row0 + r;
            if (row < n)
                hv = *reinterpret_cast<const float4*>(&H[(size_t)row * DD + kc * 32 + q * 4]);
            int slot = r * 8 + (q ^ ((r >> 3) & 3));
            *reinterpret_cast<float4*>(&HS[slot * 4]) = hv;
        }
        __syncthreads();
        // compute: per q (4 k's): 8 swizzled H b128 + 8 W b128 + 256 FMA
#pragma unroll
        for (int q = 0; q < 8; ++q) {
            float4 h4[8];
#pragma unroll
            for (int i = 0; i < 8; ++i) {
                int r = ty * 8 + i;
                int slot = r * 8 + (q ^ (ty & 3));
                h4[i] = *reinterpret_cast<const float4*>(&HS[slot * 4]);
            }
#pragma unroll
            for (int dk = 0; dk < 4; ++dk) {
                int k = q * 4 + dk;
                float4 w0 = *reinterpret_cast<const float4*>(&WS[k * 128 + c0]);
                float4 w1 = *reinterpret_cast<const float4*>(&WS[k * 128 + c1]);
#pragma unroll
                for (int i = 0; i < 8; ++i) {
                    float hv = (dk == 0) ? h4[i].x : (dk == 1) ? h4[i].y
                             : (dk == 2) ? h4[i].z : h4[i].w;
                    acc0[i][0] = fmaf(hv, w0.x, acc0[i][0]);
                    acc0[i][1] = fmaf(hv, w0.y, acc0[i][1]);
                    acc0[i][2] = fmaf(hv, w0.z, acc0[i][2]);
                    acc0[i][3] = fmaf(hv, w0.w, acc0[i][3]);
                    acc1[i][0] = fmaf(hv, w1.x, acc1[i][0]);
                    acc1[i][1] = fmaf(hv, w1.y, acc1[i][1]);
                    acc1[i][2] = fmaf(hv, w1.z, acc1[i][2]);
                    acc1[i][3] = fmaf(hv, w1.w, acc1[i][3]);
                }
            }
        }
    }
    // epilogue: bias + relu + store
    float4 b0 = *reinterpret_cast<const float4*>(&bias[c0]);
    float4 b1 = *reinterpret_cast<const float4*>(&bias[c1]);
#pragma unroll
    for (int i = 0; i < 8; ++i) {
        int row = row0 + ty * 8 + i;
        if (row < n) {
            float4 o0, o1;
            o0.x = fmaxf(acc0[i][0] + b0.x, 0.f);
            o0.y = fmaxf(acc0[i][1] + b0.y, 0.f);
            o0.z = fmaxf(acc0[i][2] + b0.z, 0.f);
            o0.w = fmaxf(acc0[i][3] + b0.w, 0.f);
            o1.x = fmaxf(acc1[i][0] + b1.x, 0.f);
            o1.y = fmaxf(acc1[i][1] + b1.y, 0.f);
            o1.z = fmaxf(acc1[i][2] + b1.z, 0.f);
            o1.w = fmaxf(acc1[i][3] + b1.w, 0.f);
            *reinterpret_cast<float4*>(&O[(size_t)row * DD + c0]) = o0;
            *reinterpret_cast<float4*>(&O[(size_t)row * DD + c1]) = o1;
        }
    }
}

// ---------------------------------------------------------------------------
// out[i] = dot(H[i,:], Wout) + bout   (one wave per row)
// ---------------------------------------------------------------------------
__global__ __launch_bounds__(256) void out_dot(
    const float* __restrict__ H, const float* __restrict__ Wout,
    const float* __restrict__ bout, float* __restrict__ out, int n)
{
    int wid  = (blockIdx.x * 256 + threadIdx.x) >> 6;
    int lane = threadIdx.x & 63;
    if (wid >= n) return;
    float2 h2 = *reinterpret_cast<const float2*>(&H[(size_t)wid * DD + lane * 2]);
    float2 w2 = *reinterpret_cast<const float2*>(&Wout[lane * 2]);
    float v = h2.x * w2.x + h2.y * w2.y;
#pragma unroll
    for (int off = 32; off > 0; off >>= 1) v += __shfl_down(v, off, 64);
    if (lane == 0) out[wid] = v + bout[0];
}

extern "C" void kernel_launch(void* const* d_in, const int* in_sizes, int n_in,
                              void* d_out, int out_size, void* d_ws, size_t ws_size,
                              hipStream_t stream)
{
    const float* x    = (const float*)d_in[0];
    const int*   esrc = (const int*)  d_in[1];
    const int*   edst = (const int*)  d_in[2];
    const float* eval = (const float*)d_in[3];
    const float* W1   = (const float*)d_in[4];
    const float* b1   = (const float*)d_in[5];
    const float* W2   = (const float*)d_in[6];
    const float* b2   = (const float*)d_in[7];
    const float* Wout = (const float*)d_in[8];
    const float* bout = (const float*)d_in[9];
    float* out = (float*)d_out;

    float* bufA = (float*)d_ws;                         // [N][128] spmm accum
    float* bufB = bufA + (size_t)NN * DD;               // [N][128] linear out
    const size_t rowBytes = (size_t)NN * DD * sizeof(float);

    const int spmmGrid = (EE * 32) / 256;               // 200000
    const int linGrid  = (NN + 127) / 128;              // 782
    const int dotGrid  = (NN + 3) / 4;                  // 25000

    // layer 1
    hipMemsetAsync(bufA, 0, rowBytes, stream);
    spmm_atomic<<<spmmGrid, 256, 0, stream>>>(x, esrc, edst, eval, bufA, EE);
    linear_relu<<<linGrid, 256, 0, stream>>>(bufA, W1, b1, bufB, NN);
    // layer 2
    hipMemsetAsync(bufA, 0, rowBytes, stream);
    spmm_atomic<<<spmmGrid, 256, 0, stream>>>(bufB, esrc, edst, eval, bufA, EE);
    linear_relu<<<linGrid, 256, 0, stream>>>(bufA, W2, b2, bufB, NN);
    // output head
    out_dot<<<dotGrid, 256, 0, stream>>>(bufB, Wout, bout, out, NN);
}

// Round 2
// 766.067 us; speedup vs baseline: 7.1909x; 7.1909x over previous
//
#include <hip/hip_runtime.h>

#define NN 100000
#define EE 1600000
#define DD 128

// ---------------------------------------------------------------------------
// CSR build step 1: histogram of destination degrees
// ---------------------------------------------------------------------------
__global__ __launch_bounds__(256) void hist_kernel(
    const int* __restrict__ dst, int* __restrict__ deg, int E)
{
    int e = blockIdx.x * 256 + threadIdx.x;
    if (e < E) atomicAdd(&deg[dst[e]], 1);
}

// ---------------------------------------------------------------------------
// CSR build step 2: exclusive scan of deg -> rowptr (N+1), copy -> next
// single block of 1024 threads; N=100000 -> chunk of 98 per thread
// ---------------------------------------------------------------------------
__global__ __launch_bounds__(1024) void scan_kernel(
    const int* __restrict__ deg, int* __restrict__ rowptr,
    int* __restrict__ next, int n)
{
    __shared__ int s[1024];
    const int t = threadIdx.x;
    const int chunk = (n + 1023) / 1024;
    const int lo = t * chunk;
    const int hi = min(n, lo + chunk);
    int sum = 0;
    for (int i = lo; i < hi; ++i) sum += deg[i];
    s[t] = sum;
    __syncthreads();
    // Hillis-Steele inclusive scan over 1024 partials
    for (int off = 1; off < 1024; off <<= 1) {
        int v = (t >= off) ? s[t - off] : 0;
        __syncthreads();
        s[t] += v;
        __syncthreads();
    }
    int run = (t == 0) ? 0 : s[t - 1];
    for (int i = lo; i < hi; ++i) {
        int d = deg[i];
        rowptr[i] = run;
        next[i]   = run;
        run += d;
    }
    if (t == 1023) rowptr[n] = s[1023];
}

// ---------------------------------------------------------------------------
// CSR build step 3: scatter edges into dst-sorted arrays
// ---------------------------------------------------------------------------
__global__ __launch_bounds__(256) void scatter_kernel(
    const int* __restrict__ src, const int* __restrict__ dst,
    const float* __restrict__ val, int* __restrict__ next,
    int* __restrict__ csrc, float* __restrict__ cval, int E)
{
    int e = blockIdx.x * 256 + threadIdx.x;
    if (e >= E) return;
    int d = dst[e];
    int p = atomicAdd(&next[d], 1);
    csrc[p] = src[e];
    cval[p] = val[e];
}

// ---------------------------------------------------------------------------
// SpMM-CSR: out[i,:] = sum_e val[e] * H[src[e],:]  — one wave per row,
// float2 per lane (64 lanes * 2 = 128 cols), ILP-4 edge unroll, no atomics.
// ---------------------------------------------------------------------------
__global__ __launch_bounds__(256) void spmm_csr(
    const float* __restrict__ H, const int* __restrict__ rowptr,
    const int* __restrict__ csrc, const float* __restrict__ cval,
    float* __restrict__ out, int n)
{
    int w = (blockIdx.x * 256 + threadIdx.x) >> 6;
    if (w >= n) return;
    int lane = threadIdx.x & 63;
    int beg = rowptr[w];
    int end = rowptr[w + 1];
    float accx = 0.f, accy = 0.f;
    int e = beg;
    for (; e + 4 <= end; e += 4) {
        int s0 = csrc[e + 0], s1 = csrc[e + 1], s2 = csrc[e + 2], s3 = csrc[e + 3];
        float v0 = cval[e + 0], v1 = cval[e + 1], v2 = cval[e + 2], v3 = cval[e + 3];
        float2 h0 = *reinterpret_cast<const float2*>(&H[(size_t)s0 * DD + lane * 2]);
        float2 h1 = *reinterpret_cast<const float2*>(&H[(size_t)s1 * DD + lane * 2]);
        float2 h2 = *reinterpret_cast<const float2*>(&H[(size_t)s2 * DD + lane * 2]);
        float2 h3 = *reinterpret_cast<const float2*>(&H[(size_t)s3 * DD + lane * 2]);
        accx = fmaf(v0, h0.x, accx); accy = fmaf(v0, h0.y, accy);
        accx = fmaf(v1, h1.x, accx); accy = fmaf(v1, h1.y, accy);
        accx = fmaf(v2, h2.x, accx); accy = fmaf(v2, h2.y, accy);
        accx = fmaf(v3, h3.x, accx); accy = fmaf(v3, h3.y, accy);
    }
    for (; e < end; ++e) {
        int s0 = csrc[e];
        float v0 = cval[e];
        float2 h0 = *reinterpret_cast<const float2*>(&H[(size_t)s0 * DD + lane * 2]);
        accx = fmaf(v0, h0.x, accx); accy = fmaf(v0, h0.y, accy);
    }
    float2 o; o.x = accx; o.y = accy;
    *reinterpret_cast<float2*>(&out[(size_t)w * DD + lane * 2]) = o;
}

// ---------------------------------------------------------------------------
// O = relu(H @ W + b)   H:[n][128]  W:[128][128]  b:[128]
// ---------------------------------------------------------------------------
__global__ __launch_bounds__(256) void linear_relu(
    const float* __restrict__ H, const float* __restrict__ W,
    const float* __restrict__ bias, float* __restrict__ O, int n)
{
    __shared__ float WS[32 * 128];   // [kk][c]
    __shared__ float HS[128 * 32];   // [r][kk], float4 slots swizzled by row-group
    const int t  = threadIdx.x;
    const int tx = t & 15;
    const int ty = t >> 4;
    const int row0 = blockIdx.x * 128;
    const int c0 = tx * 4;
    const int c1 = 64 + tx * 4;

    float acc0[8][4];
    float acc1[8][4];
#pragma unroll
    for (int i = 0; i < 8; ++i)
#pragma unroll
        for (int j = 0; j < 4; ++j) { acc0[i][j] = 0.f; acc1[i][j] = 0.f; }

    for (int kc = 0; kc < 4; ++kc) {
        __syncthreads();
#pragma unroll
        for (int g = 0; g < 4; ++g) {
            int idx = t + g * 256;
            int kk  = idx >> 5;
            int c4  = (idx & 31) * 4;
            *reinterpret_cast<float4*>(&WS[kk * 128 + c4]) =
                *reinterpret_cast<const float4*>(&W[(size_t)(kc * 32 + kk) * 128 + c4]);
        }
#pragma unroll
        for (int g = 0; g < 4; ++g) {
            int idx = t + g * 256;
            int r = idx >> 3;
            int q = idx & 7;
            float4 hv = make_float4(0.f, 0.f, 0.f, 0.f);
            int row = row0 + r;
            if (row < n)
                hv = *reinterpret_cast<const float4*>(&H[(size_t)row * DD + kc * 32 + q * 4]);
            int slot = r * 8 + (q ^ ((r >> 3) & 3));
            *reinterpret_cast<float4*>(&HS[slot * 4]) = hv;
        }
        __syncthreads();
#pragma unroll
        for (int q = 0; q < 8; ++q) {
            float4 h4[8];
#pragma unroll
            for (int i = 0; i < 8; ++i) {
                int r = ty * 8 + i;
                int slot = r * 8 + (q ^ (ty & 3));
                h4[i] = *reinterpret_cast<const float4*>(&HS[slot * 4]);
            }
#pragma unroll
            for (int dk = 0; dk < 4; ++dk) {
                int k = q * 4 + dk;
                float4 w0 = *reinterpret_cast<const float4*>(&WS[k * 128 + c0]);
                float4 w1 = *reinterpret_cast<const float4*>(&WS[k * 128 + c1]);
#pragma unroll
                for (int i = 0; i < 8; ++i) {
                    float hv = (dk == 0) ? h4[i].x : (dk == 1) ? h4[i].y
                             : (dk == 2) ? h4[i].z : h4[i].w;
                    acc0[i][0] = fmaf(hv, w0.x, acc0[i][0]);
                    acc0[i][1] = fmaf(hv, w0.y, acc0[i][1]);
                    acc0[i][2] = fmaf(hv, w0.z, acc0[i][2]);
                    acc0[i][3] = fmaf(hv, w0.w, acc0[i][3]);
                    acc1[i][0] = fmaf(hv, w1.x, acc1[i][0]);
                    acc1[i][1] = fmaf(hv, w1.y, acc1[i][1]);
                    acc1[i][2] = fmaf(hv, w1.z, acc1[i][2]);
                    acc1[i][3] = fmaf(hv, w1.w, acc1[i][3]);
                }
            }
        }
    }
    float4 b0 = *reinterpret_cast<const float4*>(&bias[c0]);
    float4 b1 = *reinterpret_cast<const float4*>(&bias[c1]);
#pragma unroll
    for (int i = 0; i < 8; ++i) {
        int row = row0 + ty * 8 + i;
        if (row < n) {
            float4 o0, o1;
            o0.x = fmaxf(acc0[i][0] + b0.x, 0.f);
            o0.y = fmaxf(acc0[i][1] + b0.y, 0.f);
            o0.z = fmaxf(acc0[i][2] + b0.z, 0.f);
            o0.w = fmaxf(acc0[i][3] + b0.w, 0.f);
            o1.x = fmaxf(acc1[i][0] + b1.x, 0.f);
            o1.y = fmaxf(acc1[i][1] + b1.y, 0.f);
            o1.z = fmaxf(acc1[i][2] + b1.z, 0.f);
            o1.w = fmaxf(acc1[i][3] + b1.w, 0.f);
            *reinterpret_cast<float4*>(&O[(size_t)row * DD + c0]) = o0;
            *reinterpret_cast<float4*>(&O[(size_t)row * DD + c1]) = o1;
        }
    }
}

// ---------------------------------------------------------------------------
// out[i] = dot(H[i,:], Wout) + bout   (one wave per row)
// ---------------------------------------------------------------------------
__global__ __launch_bounds__(256) void out_dot(
    const float* __restrict__ H, const float* __restrict__ Wout,
    const float* __restrict__ bout, float* __restrict__ out, int n)
{
    int wid  = (blockIdx.x * 256 + threadIdx.x) >> 6;
    int lane = threadIdx.x & 63;
    if (wid >= n) return;
    float2 h2 = *reinterpret_cast<const float2*>(&H[(size_t)wid * DD + lane * 2]);
    float2 w2 = *reinterpret_cast<const float2*>(&Wout[lane * 2]);
    float v = h2.x * w2.x + h2.y * w2.y;
#pragma unroll
    for (int off = 32; off > 0; off >>= 1) v += __shfl_down(v, off, 64);
    if (lane == 0) out[wid] = v + bout[0];
}

extern "C" void kernel_launch(void* const* d_in, const int* in_sizes, int n_in,
                              void* d_out, int out_size, void* d_ws, size_t ws_size,
                              hipStream_t stream)
{
    const float* x    = (const float*)d_in[0];
    const int*   esrc = (const int*)  d_in[1];
    const int*   edst = (const int*)  d_in[2];
    const float* eval = (const float*)d_in[3];
    const float* W1   = (const float*)d_in[4];
    const float* b1   = (const float*)d_in[5];
    const float* W2   = (const float*)d_in[6];
    const float* b2   = (const float*)d_in[7];
    const float* Wout = (const float*)d_in[8];
    const float* bout = (const float*)d_in[9];
    float* out = (float*)d_out;

    // workspace layout
    float* bufA   = (float*)d_ws;                        // [N][128]
    float* bufB   = bufA + (size_t)NN * DD;              // [N][128]
    int*   deg    = (int*)(bufB + (size_t)NN * DD);      // [N]
    int*   rowptr = deg + NN;                            // [N+1]
    int*   next   = rowptr + (NN + 1);                   // [N]
    int*   csrc   = next + NN;                           // [E]
    float* cval   = (float*)(csrc + EE);                 // [E]

    const int histGrid = (EE + 255) / 256;
    const int spmmGrid = (NN * 64 + 255) / 256;
    const int linGrid  = (NN + 127) / 128;
    const int dotGrid  = (NN + 3) / 4;

    // --- build CSR (once per call; reused by both layers) ---
    hipMemsetAsync(deg, 0, NN * sizeof(int), stream);
    hist_kernel<<<histGrid, 256, 0, stream>>>(edst, deg, EE);
    scan_kernel<<<1, 1024, 0, stream>>>(deg, rowptr, next, NN);
    scatter_kernel<<<histGrid, 256, 0, stream>>>(esrc, edst, eval, next, csrc, cval, EE);

    // --- layer 1 ---
    spmm_csr<<<spmmGrid, 256, 0, stream>>>(x, rowptr, csrc, cval, bufA, NN);
    linear_relu<<<linGrid, 256, 0, stream>>>(bufA, W1, b1, bufB, NN);
    // --- layer 2 ---
    spmm_csr<<<spmmGrid, 256, 0, stream>>>(bufB, rowptr, csrc, cval, bufA, NN);
    linear_relu<<<linGrid, 256, 0, stream>>>(bufA, W2, b2, bufB, NN);
    // --- output head ---
    out_dot<<<dotGrid, 256, 0, stream>>>(bufB, Wout, bout, out, NN);
}

// Round 3
// 573.229 us; speedup vs baseline: 9.6100x; 1.3364x over previous
//
#include <hip/hip_runtime.h>

#define NN 100000
#define EE 1600000
#define DD 128
#define NB ((NN + 255) / 256)   // 391 scan blocks

// ---------------------------------------------------------------------------
// CSR build step 1: histogram of destination degrees
// ---------------------------------------------------------------------------
__global__ __launch_bounds__(256) void hist_kernel(
    const int* __restrict__ dst, int* __restrict__ deg, int E)
{
    int e = blockIdx.x * 256 + threadIdx.x;
    if (e < E) atomicAdd(&deg[dst[e]], 1);
}

// ---------------------------------------------------------------------------
// Two-level exclusive scan of deg[N] -> rowptr[N+1] (+ copy into next[N])
// ---------------------------------------------------------------------------
__global__ __launch_bounds__(256) void reduce_deg(
    const int* __restrict__ deg, int* __restrict__ blockSums, int n)
{
    __shared__ int s[256];
    int i = blockIdx.x * 256 + threadIdx.x;
    s[threadIdx.x] = (i < n) ? deg[i] : 0;
    __syncthreads();
#pragma unroll
    for (int off = 128; off > 0; off >>= 1) {
        if (threadIdx.x < off) s[threadIdx.x] += s[threadIdx.x + off];
        __syncthreads();
    }
    if (threadIdx.x == 0) blockSums[blockIdx.x] = s[0];
}

__global__ __launch_bounds__(512) void scan_sums(
    int* __restrict__ blockSums, int nb)
{
    __shared__ int s[512];
    int t = threadIdx.x;
    int v = (t < nb) ? blockSums[t] : 0;
    s[t] = v;
    __syncthreads();
    for (int off = 1; off < 512; off <<= 1) {
        int u = (t >= off) ? s[t - off] : 0;
        __syncthreads();
        s[t] += u;
        __syncthreads();
    }
    if (t < nb) blockSums[t] = s[t] - v;   // exclusive
}

__global__ __launch_bounds__(256) void scan_block(
    const int* __restrict__ deg, const int* __restrict__ blockSums,
    int* __restrict__ rowptr, int* __restrict__ next, int n)
{
    __shared__ int s[256];
    int i = blockIdx.x * 256 + threadIdx.x;
    int v = (i < n) ? deg[i] : 0;
    s[threadIdx.x] = v;
    __syncthreads();
    for (int off = 1; off < 256; off <<= 1) {
        int u = (threadIdx.x >= off) ? s[threadIdx.x - off] : 0;
        __syncthreads();
        s[threadIdx.x] += u;
        __syncthreads();
    }
    int excl = s[threadIdx.x] - v + blockSums[blockIdx.x];
    if (i < n) { rowptr[i] = excl; next[i] = excl; }
    if (i == n - 1) rowptr[n] = excl + v;
}

// ---------------------------------------------------------------------------
// CSR build step 3: scatter edges into dst-sorted arrays
// ---------------------------------------------------------------------------
__global__ __launch_bounds__(256) void scatter_kernel(
    const int* __restrict__ src, const int* __restrict__ dst,
    const float* __restrict__ val, int* __restrict__ next,
    int* __restrict__ csrc, float* __restrict__ cval, int E)
{
    int e = blockIdx.x * 256 + threadIdx.x;
    if (e >= E) return;
    int d = dst[e];
    int p = atomicAdd(&next[d], 1);
    csrc[p] = src[e];
    cval[p] = val[e];
}

// ---------------------------------------------------------------------------
// SpMM-CSR: out[i,:] = sum_e val[e] * H[src[e],:]  — one wave per row,
// float2 per lane (64 lanes * 2 = 128 cols), ILP-4 edge unroll, no atomics.
// ---------------------------------------------------------------------------
__global__ __launch_bounds__(256) void spmm_csr(
    const float* __restrict__ H, const int* __restrict__ rowptr,
    const int* __restrict__ csrc, const float* __restrict__ cval,
    float* __restrict__ out, int n)
{
    int w = (blockIdx.x * 256 + threadIdx.x) >> 6;
    if (w >= n) return;
    int lane = threadIdx.x & 63;
    int beg = rowptr[w];
    int end = rowptr[w + 1];
    float accx = 0.f, accy = 0.f;
    int e = beg;
    for (; e + 4 <= end; e += 4) {
        int s0 = csrc[e + 0], s1 = csrc[e + 1], s2 = csrc[e + 2], s3 = csrc[e + 3];
        float v0 = cval[e + 0], v1 = cval[e + 1], v2 = cval[e + 2], v3 = cval[e + 3];
        float2 h0 = *reinterpret_cast<const float2*>(&H[(size_t)s0 * DD + lane * 2]);
        float2 h1 = *reinterpret_cast<const float2*>(&H[(size_t)s1 * DD + lane * 2]);
        float2 h2 = *reinterpret_cast<const float2*>(&H[(size_t)s2 * DD + lane * 2]);
        float2 h3 = *reinterpret_cast<const float2*>(&H[(size_t)s3 * DD + lane * 2]);
        accx = fmaf(v0, h0.x, accx); accy = fmaf(v0, h0.y, accy);
        accx = fmaf(v1, h1.x, accx); accy = fmaf(v1, h1.y, accy);
        accx = fmaf(v2, h2.x, accx); accy = fmaf(v2, h2.y, accy);
        accx = fmaf(v3, h3.x, accx); accy = fmaf(v3, h3.y, accy);
    }
    for (; e < end; ++e) {
        int s0 = csrc[e];
        float v0 = cval[e];
        float2 h0 = *reinterpret_cast<const float2*>(&H[(size_t)s0 * DD + lane * 2]);
        accx = fmaf(v0, h0.x, accx); accy = fmaf(v0, h0.y, accy);
    }
    float2 o; o.x = accx; o.y = accy;
    *reinterpret_cast<float2*>(&out[(size_t)w * DD + lane * 2]) = o;
}

// ---------------------------------------------------------------------------
// O = relu(H @ W + b)   H:[n][128]  W:[128][128]  b:[128]
// ---------------------------------------------------------------------------
__global__ __launch_bounds__(256) void linear_relu(
    const float* __restrict__ H, const float* __restrict__ W,
    const float* __restrict__ bias, float* __restrict__ O, int n)
{
    __shared__ float WS[32 * 128];   // [kk][c]
    __shared__ float HS[128 * 32];   // [r][kk], float4 slots swizzled by row-group
    const int t  = threadIdx.x;
    const int tx = t & 15;
    const int ty = t >> 4;
    const int row0 = blockIdx.x * 128;
    const int c0 = tx * 4;
    const int c1 = 64 + tx * 4;

    float acc0[8][4];
    float acc1[8][4];
#pragma unroll
    for (int i = 0; i < 8; ++i)
#pragma unroll
        for (int j = 0; j < 4; ++j) { acc0[i][j] = 0.f; acc1[i][j] = 0.f; }

    for (int kc = 0; kc < 4; ++kc) {
        __syncthreads();
#pragma unroll
        for (int g = 0; g < 4; ++g) {
            int idx = t + g * 256;
            int kk  = idx >> 5;
            int c4  = (idx & 31) * 4;
            *reinterpret_cast<float4*>(&WS[kk * 128 + c4]) =
                *reinterpret_cast<const float4*>(&W[(size_t)(kc * 32 + kk) * 128 + c4]);
        }
#pragma unroll
        for (int g = 0; g < 4; ++g) {
            int idx = t + g * 256;
            int r = idx >> 3;
            int q = idx & 7;
            float4 hv = make_float4(0.f, 0.f, 0.f, 0.f);
            int row = row0 + r;
            if (row < n)
                hv = *reinterpret_cast<const float4*>(&H[(size_t)row * DD + kc * 32 + q * 4]);
            int slot = r * 8 + (q ^ ((r >> 3) & 3));
            *reinterpret_cast<float4*>(&HS[slot * 4]) = hv;
        }
        __syncthreads();
#pragma unroll
        for (int q = 0; q < 8; ++q) {
            float4 h4[8];
#pragma unroll
            for (int i = 0; i < 8; ++i) {
                int r = ty * 8 + i;
                int slot = r * 8 + (q ^ (ty & 3));
                h4[i] = *reinterpret_cast<const float4*>(&HS[slot * 4]);
            }
#pragma unroll
            for (int dk = 0; dk < 4; ++dk) {
                int k = q * 4 + dk;
                float4 w0 = *reinterpret_cast<const float4*>(&WS[k * 128 + c0]);
                float4 w1 = *reinterpret_cast<const float4*>(&WS[k * 128 + c1]);
#pragma unroll
                for (int i = 0; i < 8; ++i) {
                    float hv = (dk == 0) ? h4[i].x : (dk == 1) ? h4[i].y
                             : (dk == 2) ? h4[i].z : h4[i].w;
                    acc0[i][0] = fmaf(hv, w0.x, acc0[i][0]);
                    acc0[i][1] = fmaf(hv, w0.y, acc0[i][1]);
                    acc0[i][2] = fmaf(hv, w0.z, acc0[i][2]);
                    acc0[i][3] = fmaf(hv, w0.w, acc0[i][3]);
                    acc1[i][0] = fmaf(hv, w1.x, acc1[i][0]);
                    acc1[i][1] = fmaf(hv, w1.y, acc1[i][1]);
                    acc1[i][2] = fmaf(hv, w1.z, acc1[i][2]);
                    acc1[i][3] = fmaf(hv, w1.w, acc1[i][3]);
                }
            }
        }
    }
    float4 b0 = *reinterpret_cast<const float4*>(&bias[c0]);
    float4 b1 = *reinterpret_cast<const float4*>(&bias[c1]);
#pragma unroll
    for (int i = 0; i < 8; ++i) {
        int row = row0 + ty * 8 + i;
        if (row < n) {
            float4 o0, o1;
            o0.x = fmaxf(acc0[i][0] + b0.x, 0.f);
            o0.y = fmaxf(acc0[i][1] + b0.y, 0.f);
            o0.z = fmaxf(acc0[i][2] + b0.z, 0.f);
            o0.w = fmaxf(acc0[i][3] + b0.w, 0.f);
            o1.x = fmaxf(acc1[i][0] + b1.x, 0.f);
            o1.y = fmaxf(acc1[i][1] + b1.y, 0.f);
            o1.z = fmaxf(acc1[i][2] + b1.z, 0.f);
            o1.w = fmaxf(acc1[i][3] + b1.w, 0.f);
            *reinterpret_cast<float4*>(&O[(size_t)row * DD + c0]) = o0;
            *reinterpret_cast<float4*>(&O[(size_t)row * DD + c1]) = o1;
        }
    }
}

// ---------------------------------------------------------------------------
// out[i] = dot(H[i,:], Wout) + bout   (one wave per row)
// ---------------------------------------------------------------------------
__global__ __launch_bounds__(256) void out_dot(
    const float* __restrict__ H, const float* __restrict__ Wout,
    const float* __restrict__ bout, float* __restrict__ out, int n)
{
    int wid  = (blockIdx.x * 256 + threadIdx.x) >> 6;
    int lane = threadIdx.x & 63;
    if (wid >= n) return;
    float2 h2 = *reinterpret_cast<const float2*>(&H[(size_t)wid * DD + lane * 2]);
    float2 w2 = *reinterpret_cast<const float2*>(&Wout[lane * 2]);
    float v = h2.x * w2.x + h2.y * w2.y;
#pragma unroll
    for (int off = 32; off > 0; off >>= 1) v += __shfl_down(v, off, 64);
    if (lane == 0) out[wid] = v + bout[0];
}

extern "C" void kernel_launch(void* const* d_in, const int* in_sizes, int n_in,
                              void* d_out, int out_size, void* d_ws, size_t ws_size,
                              hipStream_t stream)
{
    const float* x    = (const float*)d_in[0];
    const int*   esrc = (const int*)  d_in[1];
    const int*   edst = (const int*)  d_in[2];
    const float* eval = (const float*)d_in[3];
    const float* W1   = (const float*)d_in[4];
    const float* b1   = (const float*)d_in[5];
    const float* W2   = (const float*)d_in[6];
    const float* b2   = (const float*)d_in[7];
    const float* Wout = (const float*)d_in[8];
    const float* bout = (const float*)d_in[9];
    float* out = (float*)d_out;

    // workspace layout
    float* bufA   = (float*)d_ws;                        // [N][128]
    float* bufB   = bufA + (size_t)NN * DD;              // [N][128]
    int*   deg    = (int*)(bufB + (size_t)NN * DD);      // [N]
    int*   rowptr = deg + NN;                            // [N+1]
    int*   next   = rowptr + (NN + 1);                   // [N]
    int*   csrc   = next + NN;                           // [E]
    float* cval   = (float*)(csrc + EE);                 // [E]
    int*   bsums  = (int*)(cval + EE);                   // [NB]

    const int histGrid = (EE + 255) / 256;
    const int spmmGrid = (NN * 64 + 255) / 256;
    const int linGrid  = (NN + 127) / 128;
    const int dotGrid  = (NN + 3) / 4;

    // --- build CSR (once per call; reused by both layers) ---
    hipMemsetAsync(deg, 0, NN * sizeof(int), stream);
    hist_kernel<<<histGrid, 256, 0, stream>>>(edst, deg, EE);
    reduce_deg<<<NB, 256, 0, stream>>>(deg, bsums, NN);
    scan_sums<<<1, 512, 0, stream>>>(bsums, NB);
    scan_block<<<NB, 256, 0, stream>>>(deg, bsums, rowptr, next, NN);
    scatter_kernel<<<histGrid, 256, 0, stream>>>(esrc, edst, eval, next, csrc, cval, EE);

    // --- layer 1 ---
    spmm_csr<<<spmmGrid, 256, 0, stream>>>(x, rowptr, csrc, cval, bufA, NN);
    linear_relu<<<linGrid, 256, 0, stream>>>(bufA, W1, b1, bufB, NN);
    // --- layer 2 ---
    spmm_csr<<<spmmGrid, 256, 0, stream>>>(bufB, rowptr, csrc, cval, bufA, NN);
    linear_relu<<<linGrid, 256, 0, stream>>>(bufA, W2, b2, bufB, NN);
    // --- output head ---
    out_dot<<<dotGrid, 256, 0, stream>>>(bufB, Wout, bout, out, NN);
}

// Round 4
// 476.023 us; speedup vs baseline: 11.5724x; 1.2042x over previous
//
#include <hip/hip_runtime.h>

#define NN 100000
#define EE 1600000
#define DD 128
#define NB ((NN + 255) / 256)   // 391 scan blocks

typedef unsigned int uint;
typedef unsigned short ushort;

__device__ inline float bf_lo(uint u) { return __uint_as_float(u << 16); }
__device__ inline float bf_hi(uint u) { return __uint_as_float(u & 0xffff0000u); }
__device__ inline ushort f2bf(float f) {           // round-to-nearest-even
    uint b = __float_as_uint(f);
    return (ushort)((b + 0x7fffu + ((b >> 16) & 1u)) >> 16);
}

// ---------------------------------------------------------------------------
// cast fp32 -> bf16 (4 elems/thread)
// ---------------------------------------------------------------------------
__global__ __launch_bounds__(256) void cast_bf16(
    const float* __restrict__ in, ushort* __restrict__ out, int n4)
{
    int i = blockIdx.x * 256 + threadIdx.x;
    if (i >= n4) return;
    float4 v = reinterpret_cast<const float4*>(in)[i];
    ushort4 o;
    o.x = f2bf(v.x); o.y = f2bf(v.y); o.z = f2bf(v.z); o.w = f2bf(v.w);
    reinterpret_cast<ushort4*>(out)[i] = o;
}

// ---------------------------------------------------------------------------
// CSR build: histogram / two-level scan / packed scatter
// ---------------------------------------------------------------------------
__global__ __launch_bounds__(256) void hist_kernel(
    const int* __restrict__ dst, int* __restrict__ deg, int E)
{
    int e = blockIdx.x * 256 + threadIdx.x;
    if (e < E) atomicAdd(&deg[dst[e]], 1);
}

__global__ __launch_bounds__(256) void reduce_deg(
    const int* __restrict__ deg, int* __restrict__ blockSums, int n)
{
    __shared__ int s[256];
    int i = blockIdx.x * 256 + threadIdx.x;
    s[threadIdx.x] = (i < n) ? deg[i] : 0;
    __syncthreads();
#pragma unroll
    for (int off = 128; off > 0; off >>= 1) {
        if (threadIdx.x < off) s[threadIdx.x] += s[threadIdx.x + off];
        __syncthreads();
    }
    if (threadIdx.x == 0) blockSums[blockIdx.x] = s[0];
}

__global__ __launch_bounds__(512) void scan_sums(
    int* __restrict__ blockSums, int nb)
{
    __shared__ int s[512];
    int t = threadIdx.x;
    int v = (t < nb) ? blockSums[t] : 0;
    s[t] = v;
    __syncthreads();
    for (int off = 1; off < 512; off <<= 1) {
        int u = (t >= off) ? s[t - off] : 0;
        __syncthreads();
        s[t] += u;
        __syncthreads();
    }
    if (t < nb) blockSums[t] = s[t] - v;   // exclusive
}

__global__ __launch_bounds__(256) void scan_block(
    const int* __restrict__ deg, const int* __restrict__ blockSums,
    int* __restrict__ rowptr, int* __restrict__ next, int n)
{
    __shared__ int s[256];
    int i = blockIdx.x * 256 + threadIdx.x;
    int v = (i < n) ? deg[i] : 0;
    s[threadIdx.x] = v;
    __syncthreads();
    for (int off = 1; off < 256; off <<= 1) {
        int u = (threadIdx.x >= off) ? s[threadIdx.x - off] : 0;
        __syncthreads();
        s[threadIdx.x] += u;
        __syncthreads();
    }
    int excl = s[threadIdx.x] - v + blockSums[blockIdx.x];
    if (i < n) { rowptr[i] = excl; next[i] = excl; }
    if (i == n - 1) rowptr[n] = excl + v;
}

__global__ __launch_bounds__(256) void scatter_kernel(
    const int* __restrict__ src, const int* __restrict__ dst,
    const float* __restrict__ val, int* __restrict__ next,
    int2* __restrict__ epk, int E)
{
    int e = blockIdx.x * 256 + threadIdx.x;
    if (e >= E) return;
    int d = dst[e];
    int p = atomicAdd(&next[d], 1);
    epk[p] = make_int2(src[e], __float_as_int(val[e]));
}

// ---------------------------------------------------------------------------
// SpMM-CSR over bf16 H: out[i,:] = sum val * H[src,:]  (fp32 accum)
// one wave/row; lane holds cols {2*lane, 2*lane+1} via one uint load.
// ---------------------------------------------------------------------------
__global__ __launch_bounds__(256) void spmm_csr_bf(
    const ushort* __restrict__ H, const int* __restrict__ rowptr,
    const int2* __restrict__ epk, float* __restrict__ out, int n)
{
    int w = (blockIdx.x * 256 + threadIdx.x) >> 6;
    if (w >= n) return;
    int lane = threadIdx.x & 63;
    int beg = rowptr[w];
    int end = rowptr[w + 1];
    float accx = 0.f, accy = 0.f;
    int e = beg;
    for (; e + 4 <= end; e += 4) {
        int2 e0 = epk[e + 0], e1 = epk[e + 1], e2 = epk[e + 2], e3 = epk[e + 3];
        uint h0 = *reinterpret_cast<const uint*>(&H[(size_t)e0.x * DD + lane * 2]);
        uint h1 = *reinterpret_cast<const uint*>(&H[(size_t)e1.x * DD + lane * 2]);
        uint h2 = *reinterpret_cast<const uint*>(&H[(size_t)e2.x * DD + lane * 2]);
        uint h3 = *reinterpret_cast<const uint*>(&H[(size_t)e3.x * DD + lane * 2]);
        float v0 = __int_as_float(e0.y), v1 = __int_as_float(e1.y);
        float v2 = __int_as_float(e2.y), v3 = __int_as_float(e3.y);
        accx = fmaf(v0, bf_lo(h0), accx); accy = fmaf(v0, bf_hi(h0), accy);
        accx = fmaf(v1, bf_lo(h1), accx); accy = fmaf(v1, bf_hi(h1), accy);
        accx = fmaf(v2, bf_lo(h2), accx); accy = fmaf(v2, bf_hi(h2), accy);
        accx = fmaf(v3, bf_lo(h3), accx); accy = fmaf(v3, bf_hi(h3), accy);
    }
    for (; e < end; ++e) {
        int2 e0 = epk[e];
        uint h0 = *reinterpret_cast<const uint*>(&H[(size_t)e0.x * DD + lane * 2]);
        float v0 = __int_as_float(e0.y);
        accx = fmaf(v0, bf_lo(h0), accx); accy = fmaf(v0, bf_hi(h0), accy);
    }
    float2 o; o.x = accx; o.y = accy;
    *reinterpret_cast<float2*>(&out[(size_t)w * DD + lane * 2]) = o;
}

// ---------------------------------------------------------------------------
// O_bf16 = relu(H @ W + b)   H fp32 [n][128] -> O bf16 [n][128]
// ---------------------------------------------------------------------------
__global__ __launch_bounds__(256) void linear_relu_bf(
    const float* __restrict__ H, const float* __restrict__ W,
    const float* __restrict__ bias, ushort* __restrict__ O, int n)
{
    __shared__ float WS[32 * 128];
    __shared__ float HS[128 * 32];
    const int t  = threadIdx.x;
    const int tx = t & 15;
    const int ty = t >> 4;
    const int row0 = blockIdx.x * 128;
    const int c0 = tx * 4;
    const int c1 = 64 + tx * 4;

    float acc0[8][4], acc1[8][4];
#pragma unroll
    for (int i = 0; i < 8; ++i)
#pragma unroll
        for (int j = 0; j < 4; ++j) { acc0[i][j] = 0.f; acc1[i][j] = 0.f; }

    for (int kc = 0; kc < 4; ++kc) {
        __syncthreads();
#pragma unroll
        for (int g = 0; g < 4; ++g) {
            int idx = t + g * 256;
            int kk  = idx >> 5;
            int c4  = (idx & 31) * 4;
            *reinterpret_cast<float4*>(&WS[kk * 128 + c4]) =
                *reinterpret_cast<const float4*>(&W[(size_t)(kc * 32 + kk) * 128 + c4]);
        }
#pragma unroll
        for (int g = 0; g < 4; ++g) {
            int idx = t + g * 256;
            int r = idx >> 3;
            int q = idx & 7;
            float4 hv = make_float4(0.f, 0.f, 0.f, 0.f);
            int row = row0 + r;
            if (row < n)
                hv = *reinterpret_cast<const float4*>(&H[(size_t)row * DD + kc * 32 + q * 4]);
            int slot = r * 8 + (q ^ ((r >> 3) & 3));
            *reinterpret_cast<float4*>(&HS[slot * 4]) = hv;
        }
        __syncthreads();
#pragma unroll
        for (int q = 0; q < 8; ++q) {
            float4 h4[8];
#pragma unroll
            for (int i = 0; i < 8; ++i) {
                int r = ty * 8 + i;
                int slot = r * 8 + (q ^ (ty & 3));
                h4[i] = *reinterpret_cast<const float4*>(&HS[slot * 4]);
            }
#pragma unroll
            for (int dk = 0; dk < 4; ++dk) {
                int k = q * 4 + dk;
                float4 w0 = *reinterpret_cast<const float4*>(&WS[k * 128 + c0]);
                float4 w1 = *reinterpret_cast<const float4*>(&WS[k * 128 + c1]);
#pragma unroll
                for (int i = 0; i < 8; ++i) {
                    float hv = (dk == 0) ? h4[i].x : (dk == 1) ? h4[i].y
                             : (dk == 2) ? h4[i].z : h4[i].w;
                    acc0[i][0] = fmaf(hv, w0.x, acc0[i][0]);
                    acc0[i][1] = fmaf(hv, w0.y, acc0[i][1]);
                    acc0[i][2] = fmaf(hv, w0.z, acc0[i][2]);
                    acc0[i][3] = fmaf(hv, w0.w, acc0[i][3]);
                    acc1[i][0] = fmaf(hv, w1.x, acc1[i][0]);
                    acc1[i][1] = fmaf(hv, w1.y, acc1[i][1]);
                    acc1[i][2] = fmaf(hv, w1.z, acc1[i][2]);
                    acc1[i][3] = fmaf(hv, w1.w, acc1[i][3]);
                }
            }
        }
    }
    float4 b0 = *reinterpret_cast<const float4*>(&bias[c0]);
    float4 b1 = *reinterpret_cast<const float4*>(&bias[c1]);
#pragma unroll
    for (int i = 0; i < 8; ++i) {
        int row = row0 + ty * 8 + i;
        if (row < n) {
            ushort4 o0, o1;
            o0.x = f2bf(fmaxf(acc0[i][0] + b0.x, 0.f));
            o0.y = f2bf(fmaxf(acc0[i][1] + b0.y, 0.f));
            o0.z = f2bf(fmaxf(acc0[i][2] + b0.z, 0.f));
            o0.w = f2bf(fmaxf(acc0[i][3] + b0.w, 0.f));
            o1.x = f2bf(fmaxf(acc1[i][0] + b1.x, 0.f));
            o1.y = f2bf(fmaxf(acc1[i][1] + b1.y, 0.f));
            o1.z = f2bf(fmaxf(acc1[i][2] + b1.z, 0.f));
            o1.w = f2bf(fmaxf(acc1[i][3] + b1.w, 0.f));
            *reinterpret_cast<ushort4*>(&O[(size_t)row * DD + c0]) = o0;
            *reinterpret_cast<ushort4*>(&O[(size_t)row * DD + c1]) = o1;
        }
    }
}

// ---------------------------------------------------------------------------
// out[row] = relu(H @ W + b) . Wout + bout   (layer-2 linear fused with head)
// ---------------------------------------------------------------------------
__global__ __launch_bounds__(256) void linear_dot(
    const float* __restrict__ H, const float* __restrict__ W,
    const float* __restrict__ bias, const float* __restrict__ Wout,
    const float* __restrict__ bout, float* __restrict__ out, int n)
{
    __shared__ float WS[32 * 128];
    __shared__ float HS[128 * 32];
    const int t  = threadIdx.x;
    const int tx = t & 15;
    const int ty = t >> 4;
    const int row0 = blockIdx.x * 128;
    const int c0 = tx * 4;
    const int c1 = 64 + tx * 4;

    float acc0[8][4], acc1[8][4];
#pragma unroll
    for (int i = 0; i < 8; ++i)
#pragma unroll
        for (int j = 0; j < 4; ++j) { acc0[i][j] = 0.f; acc1[i][j] = 0.f; }

    for (int kc = 0; kc < 4; ++kc) {
        __syncthreads();
#pragma unroll
        for (int g = 0; g < 4; ++g) {
            int idx = t + g * 256;
            int kk  = idx >> 5;
            int c4  = (idx & 31) * 4;
            *reinterpret_cast<float4*>(&WS[kk * 128 + c4]) =
                *reinterpret_cast<const float4*>(&W[(size_t)(kc * 32 + kk) * 128 + c4]);
        }
#pragma unroll
        for (int g = 0; g < 4; ++g) {
            int idx = t + g * 256;
            int r = idx >> 3;
            int q = idx & 7;
            float4 hv = make_float4(0.f, 0.f, 0.f, 0.f);
            int row = row0 + r;
            if (row < n)
                hv = *reinterpret_cast<const float4*>(&H[(size_t)row * DD + kc * 32 + q * 4]);
            int slot = r * 8 + (q ^ ((r >> 3) & 3));
            *reinterpret_cast<float4*>(&HS[slot * 4]) = hv;
        }
        __syncthreads();
#pragma unroll
        for (int q = 0; q < 8; ++q) {
            float4 h4[8];
#pragma unroll
            for (int i = 0; i < 8; ++i) {
                int r = ty * 8 + i;
                int slot = r * 8 + (q ^ (ty & 3));
                h4[i] = *reinterpret_cast<const float4*>(&HS[slot * 4]);
            }
#pragma unroll
            for (int dk = 0; dk < 4; ++dk) {
                int k = q * 4 + dk;
                float4 w0 = *reinterpret_cast<const float4*>(&WS[k * 128 + c0]);
                float4 w1 = *reinterpret_cast<const float4*>(&WS[k * 128 + c1]);
#pragma unroll
                for (int i = 0; i < 8; ++i) {
                    float hv = (dk == 0) ? h4[i].x : (dk == 1) ? h4[i].y
                             : (dk == 2) ? h4[i].z : h4[i].w;
                    acc0[i][0] = fmaf(hv, w0.x, acc0[i][0]);
                    acc0[i][1] = fmaf(hv, w0.y, acc0[i][1]);
                    acc0[i][2] = fmaf(hv, w0.z, acc0[i][2]);
                    acc0[i][3] = fmaf(hv, w0.w, acc0[i][3]);
                    acc1[i][0] = fmaf(hv, w1.x, acc1[i][0]);
                    acc1[i][1] = fmaf(hv, w1.y, acc1[i][1]);
                    acc1[i][2] = fmaf(hv, w1.z, acc1[i][2]);
                    acc1[i][3] = fmaf(hv, w1.w, acc1[i][3]);
                }
            }
        }
    }
    float4 b0 = *reinterpret_cast<const float4*>(&bias[c0]);
    float4 b1 = *reinterpret_cast<const float4*>(&bias[c1]);
    float4 w0 = *reinterpret_cast<const float4*>(&Wout[c0]);
    float4 w1 = *reinterpret_cast<const float4*>(&Wout[c1]);
    float bo = bout[0];
#pragma unroll
    for (int i = 0; i < 8; ++i) {
        int row = row0 + ty * 8 + i;
        float s = fmaxf(acc0[i][0] + b0.x, 0.f) * w0.x
                + fmaxf(acc0[i][1] + b0.y, 0.f) * w0.y
                + fmaxf(acc0[i][2] + b0.z, 0.f) * w0.z
                + fmaxf(acc0[i][3] + b0.w, 0.f) * w0.w
                + fmaxf(acc1[i][0] + b1.x, 0.f) * w1.x
                + fmaxf(acc1[i][1] + b1.y, 0.f) * w1.y
                + fmaxf(acc1[i][2] + b1.z, 0.f) * w1.z
                + fmaxf(acc1[i][3] + b1.w, 0.f) * w1.w;
        s += __shfl_xor(s, 1, 64);
        s += __shfl_xor(s, 2, 64);
        s += __shfl_xor(s, 4, 64);
        s += __shfl_xor(s, 8, 64);
        if (tx == 0 && row < n) out[row] = s + bo;
    }
}

extern "C" void kernel_launch(void* const* d_in, const int* in_sizes, int n_in,
                              void* d_out, int out_size, void* d_ws, size_t ws_size,
                              hipStream_t stream)
{
    const float* x    = (const float*)d_in[0];
    const int*   esrc = (const int*)  d_in[1];
    const int*   edst = (const int*)  d_in[2];
    const float* eval = (const float*)d_in[3];
    const float* W1   = (const float*)d_in[4];
    const float* b1   = (const float*)d_in[5];
    const float* W2   = (const float*)d_in[6];
    const float* b2   = (const float*)d_in[7];
    const float* Wout = (const float*)d_in[8];
    const float* bout = (const float*)d_in[9];
    float* out = (float*)d_out;

    // workspace layout
    float*  bufA   = (float*)d_ws;                       // [N][128] fp32 spmm out
    ushort* hbf    = (ushort*)(bufA + (size_t)NN * DD);  // [N][128] bf16 spmm in
    int2*   epk    = (int2*)(hbf + (size_t)NN * DD);     // [E] packed (src,val)
    int*    deg    = (int*)(epk + EE);                   // [N]
    int*    rowptr = deg + NN;                           // [N+1]
    int*    next   = rowptr + (NN + 1);                  // [N]
    int*    bsums  = next + NN;                          // [NB]

    const int histGrid = (EE + 255) / 256;
    const int spmmGrid = (NN * 64 + 255) / 256;
    const int linGrid  = (NN + 127) / 128;
    const int castGrid = (NN * DD / 4 + 255) / 256;

    // --- build CSR (reused by both layers) ---
    hipMemsetAsync(deg, 0, NN * sizeof(int), stream);
    hist_kernel<<<histGrid, 256, 0, stream>>>(edst, deg, EE);
    reduce_deg<<<NB, 256, 0, stream>>>(deg, bsums, NN);
    scan_sums<<<1, 512, 0, stream>>>(bsums, NB);
    scan_block<<<NB, 256, 0, stream>>>(deg, bsums, rowptr, next, NN);
    scatter_kernel<<<histGrid, 256, 0, stream>>>(esrc, edst, eval, next, epk, EE);

    // --- layer 1 ---
    cast_bf16<<<castGrid, 256, 0, stream>>>(x, hbf, NN * DD / 4);
    spmm_csr_bf<<<spmmGrid, 256, 0, stream>>>(hbf, rowptr, epk, bufA, NN);
    linear_relu_bf<<<linGrid, 256, 0, stream>>>(bufA, W1, b1, hbf, NN);
    // --- layer 2 ---
    spmm_csr_bf<<<spmmGrid, 256, 0, stream>>>(hbf, rowptr, epk, bufA, NN);
    linear_dot<<<linGrid, 256, 0, stream>>>(bufA, W2, b2, Wout, bout, out, NN);
}

// Round 5
// 389.301 us; speedup vs baseline: 14.1503x; 1.2228x over previous
//
#include <hip/hip_runtime.h>

#define NN 100000
#define EE 1600000
#define DD 128
#define NB ((NN + 255) / 256)   // 391 scan blocks

typedef unsigned int uint;
typedef unsigned short ushort;
typedef float f32x4 __attribute__((ext_vector_type(4)));
typedef short bf16x8 __attribute__((ext_vector_type(8)));

__device__ inline float bf_lo(uint u) { return __uint_as_float(u << 16); }
__device__ inline float bf_hi(uint u) { return __uint_as_float(u & 0xffff0000u); }
__device__ inline ushort f2bf(float f) {           // round-to-nearest-even
    uint b = __float_as_uint(f);
    return (ushort)((b + 0x7fffu + ((b >> 16) & 1u)) >> 16);
}

// ---------------------------------------------------------------------------
// cast fp32 -> bf16 (4 elems/thread)
// ---------------------------------------------------------------------------
__global__ __launch_bounds__(256) void cast_bf16(
    const float* __restrict__ in, ushort* __restrict__ out, int n4)
{
    int i = blockIdx.x * 256 + threadIdx.x;
    if (i >= n4) return;
    float4 v = reinterpret_cast<const float4*>(in)[i];
    ushort4 o;
    o.x = f2bf(v.x); o.y = f2bf(v.y); o.z = f2bf(v.z); o.w = f2bf(v.w);
    reinterpret_cast<ushort4*>(out)[i] = o;
}

// ---------------------------------------------------------------------------
// CSR build: histogram / two-level scan / packed scatter
// ---------------------------------------------------------------------------
__global__ __launch_bounds__(256) void hist_kernel(
    const int* __restrict__ dst, int* __restrict__ deg, int E)
{
    int e = blockIdx.x * 256 + threadIdx.x;
    if (e < E) atomicAdd(&deg[dst[e]], 1);
}

__global__ __launch_bounds__(256) void reduce_deg(
    const int* __restrict__ deg, int* __restrict__ blockSums, int n)
{
    __shared__ int s[256];
    int i = blockIdx.x * 256 + threadIdx.x;
    s[threadIdx.x] = (i < n) ? deg[i] : 0;
    __syncthreads();
#pragma unroll
    for (int off = 128; off > 0; off >>= 1) {
        if (threadIdx.x < off) s[threadIdx.x] += s[threadIdx.x + off];
        __syncthreads();
    }
    if (threadIdx.x == 0) blockSums[blockIdx.x] = s[0];
}

__global__ __launch_bounds__(512) void scan_sums(
    int* __restrict__ blockSums, int nb)
{
    __shared__ int s[512];
    int t = threadIdx.x;
    int v = (t < nb) ? blockSums[t] : 0;
    s[t] = v;
    __syncthreads();
    for (int off = 1; off < 512; off <<= 1) {
        int u = (t >= off) ? s[t - off] : 0;
        __syncthreads();
        s[t] += u;
        __syncthreads();
    }
    if (t < nb) blockSums[t] = s[t] - v;   // exclusive
}

__global__ __launch_bounds__(256) void scan_block(
    const int* __restrict__ deg, const int* __restrict__ blockSums,
    int* __restrict__ rowptr, int* __restrict__ next, int n)
{
    __shared__ int s[256];
    int i = blockIdx.x * 256 + threadIdx.x;
    int v = (i < n) ? deg[i] : 0;
    s[threadIdx.x] = v;
    __syncthreads();
    for (int off = 1; off < 256; off <<= 1) {
        int u = (threadIdx.x >= off) ? s[threadIdx.x - off] : 0;
        __syncthreads();
        s[threadIdx.x] += u;
        __syncthreads();
    }
    int excl = s[threadIdx.x] - v + blockSums[blockIdx.x];
    if (i < n) { rowptr[i] = excl; next[i] = excl; }
    if (i == n - 1) rowptr[n] = excl + v;
}

// packed edge record: bits 31..15 = src (17b), bits 14..0 = val*32767
__global__ __launch_bounds__(256) void scatter_pack(
    const int* __restrict__ src, const int* __restrict__ dst,
    const float* __restrict__ val, int* __restrict__ next,
    uint* __restrict__ epk, int E)
{
    int e = blockIdx.x * 256 + threadIdx.x;
    if (e >= E) return;
    int d = dst[e];
    int p = atomicAdd(&next[d], 1);
    uint vq = (uint)(val[e] * 32767.f + 0.5f);
    epk[p] = ((uint)src[e] << 15) | vq;
}

// ---------------------------------------------------------------------------
// SpMM-CSR bf16 -> bf16: out[i,:] = sum val * H[src,:]  (fp32 accum)
// one wave/row; lane holds cols {2*lane, 2*lane+1} via one uint load.
// ---------------------------------------------------------------------------
__global__ __launch_bounds__(256) void spmm_bf(
    const ushort* __restrict__ H, const int* __restrict__ rowptr,
    const uint* __restrict__ epk, ushort* __restrict__ out, int n)
{
    int w = (blockIdx.x * 256 + threadIdx.x) >> 6;
    if (w >= n) return;
    int lane = threadIdx.x & 63;
    int beg = rowptr[w];
    int end = rowptr[w + 1];
    const float sc = 1.0f / 32767.f;
    float accx = 0.f, accy = 0.f;
    int e = beg;
    for (; e + 4 <= end; e += 4) {
        uint u0 = epk[e + 0], u1 = epk[e + 1], u2 = epk[e + 2], u3 = epk[e + 3];
        uint h0 = *reinterpret_cast<const uint*>(&H[(size_t)(u0 >> 15) * DD + lane * 2]);
        uint h1 = *reinterpret_cast<const uint*>(&H[(size_t)(u1 >> 15) * DD + lane * 2]);
        uint h2 = *reinterpret_cast<const uint*>(&H[(size_t)(u2 >> 15) * DD + lane * 2]);
        uint h3 = *reinterpret_cast<const uint*>(&H[(size_t)(u3 >> 15) * DD + lane * 2]);
        float v0 = (float)(u0 & 0x7fffu) * sc;
        float v1 = (float)(u1 & 0x7fffu) * sc;
        float v2 = (float)(u2 & 0x7fffu) * sc;
        float v3 = (float)(u3 & 0x7fffu) * sc;
        accx = fmaf(v0, bf_lo(h0), accx); accy = fmaf(v0, bf_hi(h0), accy);
        accx = fmaf(v1, bf_lo(h1), accx); accy = fmaf(v1, bf_hi(h1), accy);
        accx = fmaf(v2, bf_lo(h2), accx); accy = fmaf(v2, bf_hi(h2), accy);
        accx = fmaf(v3, bf_lo(h3), accx); accy = fmaf(v3, bf_hi(h3), accy);
    }
    for (; e < end; ++e) {
        uint u0 = epk[e];
        uint h0 = *reinterpret_cast<const uint*>(&H[(size_t)(u0 >> 15) * DD + lane * 2]);
        float v0 = (float)(u0 & 0x7fffu) * sc;
        accx = fmaf(v0, bf_lo(h0), accx); accy = fmaf(v0, bf_hi(h0), accy);
    }
    uint o = ((uint)f2bf(accy) << 16) | (uint)f2bf(accx);
    *reinterpret_cast<uint*>(&out[(size_t)w * DD + lane * 2]) = o;
}

// ---------------------------------------------------------------------------
// W [128][128] fp32 row-major -> bf16 MFMA B-fragment layout:
// Wp[((kk*8+ct)*64 + l)*8 + j] = bf16( W[kk*32 + (l>>4)*8 + j][ct*16 + (l&15)] )
// ---------------------------------------------------------------------------
__global__ __launch_bounds__(256) void prep_w(
    const float* __restrict__ W, ushort* __restrict__ Wp)
{
    int idx = blockIdx.x * 256 + threadIdx.x;   // 16384 total
    int j  = idx & 7;
    int l  = (idx >> 3) & 63;
    int ct = (idx >> 9) & 7;
    int kk = idx >> 12;
    int k = kk * 32 + (l >> 4) * 8 + j;
    int c = ct * 16 + (l & 15);
    Wp[idx] = f2bf(W[k * DD + c]);
}

// ---------------------------------------------------------------------------
// O = bf16(relu(A @ W + b))  via mfma_f32_16x16x32_bf16
// block = 4 waves; wave handles 16 rows x 128 cols (8 col-tiles, 4 k-steps).
// A-frag: row = l&15, k = kk*32 + (l>>4)*8 + j  (contiguous 16B load)
// C/D:    col = l&15, row = (l>>4)*4 + r        (verified layout)
// ---------------------------------------------------------------------------
__global__ __launch_bounds__(256) void linear_mfma_relu(
    const ushort* __restrict__ A, const ushort* __restrict__ Wp,
    const float* __restrict__ bias, ushort* __restrict__ O, int n)
{
    const int wv = threadIdx.x >> 6;
    const int l  = threadIdx.x & 63;
    const int row0 = blockIdx.x * 64 + wv * 16;
    const int m = l & 15, g = l >> 4;

    f32x4 acc[8];
#pragma unroll
    for (int ct = 0; ct < 8; ++ct) acc[ct] = (f32x4){0.f, 0.f, 0.f, 0.f};

#pragma unroll
    for (int kk = 0; kk < 4; ++kk) {
        bf16x8 a = *reinterpret_cast<const bf16x8*>(
            &A[(size_t)(row0 + m) * DD + kk * 32 + g * 8]);
#pragma unroll
        for (int ct = 0; ct < 8; ++ct) {
            bf16x8 b = *reinterpret_cast<const bf16x8*>(&Wp[((kk * 8 + ct) * 64 + l) * 8]);
            acc[ct] = __builtin_amdgcn_mfma_f32_16x16x32_bf16(a, b, acc[ct], 0, 0, 0);
        }
    }
#pragma unroll
    for (int ct = 0; ct < 8; ++ct) {
        int c = ct * 16 + m;
        float bb = bias[c];
#pragma unroll
        for (int r = 0; r < 4; ++r) {
            int row = row0 + g * 4 + r;
            if (row < n)
                O[(size_t)row * DD + c] = f2bf(fmaxf(acc[ct][r] + bb, 0.f));
        }
    }
}

// ---------------------------------------------------------------------------
// out[row] = relu(A @ W + b) . Wout + bout   (layer-2 linear + head, fused)
// ---------------------------------------------------------------------------
__global__ __launch_bounds__(256) void linear_mfma_dot(
    const ushort* __restrict__ A, const ushort* __restrict__ Wp,
    const float* __restrict__ bias, const float* __restrict__ Wout,
    const float* __restrict__ bout, float* __restrict__ out, int n)
{
    const int wv = threadIdx.x >> 6;
    const int l  = threadIdx.x & 63;
    const int row0 = blockIdx.x * 64 + wv * 16;
    const int m = l & 15, g = l >> 4;

    f32x4 acc[8];
#pragma unroll
    for (int ct = 0; ct < 8; ++ct) acc[ct] = (f32x4){0.f, 0.f, 0.f, 0.f};

#pragma unroll
    for (int kk = 0; kk < 4; ++kk) {
        bf16x8 a = *reinterpret_cast<const bf16x8*>(
            &A[(size_t)(row0 + m) * DD + kk * 32 + g * 8]);
#pragma unroll
        for (int ct = 0; ct < 8; ++ct) {
            bf16x8 b = *reinterpret_cast<const bf16x8*>(&Wp[((kk * 8 + ct) * 64 + l) * 8]);
            acc[ct] = __builtin_amdgcn_mfma_f32_16x16x32_bf16(a, b, acc[ct], 0, 0, 0);
        }
    }
    float srow[4] = {0.f, 0.f, 0.f, 0.f};
#pragma unroll
    for (int ct = 0; ct < 8; ++ct) {
        int c = ct * 16 + m;
        float bb = bias[c];
        float wo = Wout[c];
#pragma unroll
        for (int r = 0; r < 4; ++r)
            srow[r] = fmaf(fmaxf(acc[ct][r] + bb, 0.f), wo, srow[r]);
    }
#pragma unroll
    for (int r = 0; r < 4; ++r) {
        float s = srow[r];
        s += __shfl_xor(s, 1, 64);
        s += __shfl_xor(s, 2, 64);
        s += __shfl_xor(s, 4, 64);
        s += __shfl_xor(s, 8, 64);
        srow[r] = s;
    }
    if (m == 0) {
        float bo = bout[0];
#pragma unroll
        for (int r = 0; r < 4; ++r) {
            int row = row0 + g * 4 + r;
            if (row < n) out[row] = srow[r] + bo;
        }
    }
}

extern "C" void kernel_launch(void* const* d_in, const int* in_sizes, int n_in,
                              void* d_out, int out_size, void* d_ws, size_t ws_size,
                              hipStream_t stream)
{
    const float* x    = (const float*)d_in[0];
    const int*   esrc = (const int*)  d_in[1];
    const int*   edst = (const int*)  d_in[2];
    const float* eval = (const float*)d_in[3];
    const float* W1   = (const float*)d_in[4];
    const float* b1   = (const float*)d_in[5];
    const float* W2   = (const float*)d_in[6];
    const float* b2   = (const float*)d_in[7];
    const float* Wout = (const float*)d_in[8];
    const float* bout = (const float*)d_in[9];
    float* out = (float*)d_out;

    // workspace layout (16B-aligned segments)
    ushort* w1p    = (ushort*)d_ws;                      // [128*128]
    ushort* w2p    = w1p + 128 * 128;                    // [128*128]
    ushort* hbf    = w2p + 128 * 128;                    // [N][128] bf16 x
    ushort* bufS   = hbf + (size_t)NN * DD;              // [N][128] bf16 spmm out
    ushort* bufL   = bufS + (size_t)NN * DD;             // [N][128] bf16 linear out
    uint*   epk    = (uint*)(bufL + (size_t)NN * DD);    // [E] packed (src,val)
    int*    deg    = (int*)(epk + EE);                   // [N]
    int*    rowptr = deg + NN;                           // [N+1]
    int*    next   = rowptr + (NN + 1);                  // [N]
    int*    bsums  = next + NN;                          // [NB]

    const int histGrid = (EE + 255) / 256;
    const int spmmGrid = (NN * 64 + 255) / 256;
    const int linGrid  = (NN + 63) / 64;
    const int castGrid = (NN * DD / 4 + 255) / 256;

    // --- build CSR (reused by both layers) ---
    hipMemsetAsync(deg, 0, NN * sizeof(int), stream);
    cast_bf16<<<castGrid, 256, 0, stream>>>(x, hbf, NN * DD / 4);
    hist_kernel<<<histGrid, 256, 0, stream>>>(edst, deg, EE);
    reduce_deg<<<NB, 256, 0, stream>>>(deg, bsums, NN);
    scan_sums<<<1, 512, 0, stream>>>(bsums, NB);
    scan_block<<<NB, 256, 0, stream>>>(deg, bsums, rowptr, next, NN);
    scatter_pack<<<histGrid, 256, 0, stream>>>(esrc, edst, eval, next, epk, EE);
    prep_w<<<64, 256, 0, stream>>>(W1, w1p);
    prep_w<<<64, 256, 0, stream>>>(W2, w2p);

    // --- layer 1 ---
    spmm_bf<<<spmmGrid, 256, 0, stream>>>(hbf, rowptr, epk, bufS, NN);
    linear_mfma_relu<<<linGrid, 256, 0, stream>>>(bufS, w1p, b1, bufL, NN);
    // --- layer 2 ---
    spmm_bf<<<spmmGrid, 256, 0, stream>>>(bufL, rowptr, epk, bufS, NN);
    linear_mfma_dot<<<linGrid, 256, 0, stream>>>(bufS, w2p, b2, Wout, bout, out, NN);
}

// Round 6
// 258.399 us; speedup vs baseline: 21.3187x; 1.5066x over previous
//
#include <hip/hip_runtime.h>

#define NN 100000
#define EE 1600000
#define DD 128
#define NBK 782                 // ceil(NN/128) buckets of 128 rows
#define BINCH 8192              // edges per bucket_bin block
#define BINGRID ((EE + BINCH - 1) / BINCH)

typedef unsigned int uint;
typedef unsigned short ushort;
typedef float f32x4 __attribute__((ext_vector_type(4)));
typedef short bf16x8 __attribute__((ext_vector_type(8)));

__device__ inline float bf_lo(uint u) { return __uint_as_float(u << 16); }
__device__ inline float bf_hi(uint u) { return __uint_as_float(u & 0xffff0000u); }
__device__ inline ushort f2bf(float f) {           // round-to-nearest-even
    uint b = __float_as_uint(f);
    return (ushort)((b + 0x7fffu + ((b >> 16) & 1u)) >> 16);
}

// ---------------------------------------------------------------------------
// cast fp32 -> bf16 (4 elems/thread)
// ---------------------------------------------------------------------------
__global__ __launch_bounds__(256) void cast_bf16(
    const float* __restrict__ in, ushort* __restrict__ out, int n4)
{
    int i = blockIdx.x * 256 + threadIdx.x;
    if (i >= n4) return;
    float4 v = reinterpret_cast<const float4*>(in)[i];
    ushort4 o;
    o.x = f2bf(v.x); o.y = f2bf(v.y); o.z = f2bf(v.z); o.w = f2bf(v.w);
    reinterpret_cast<ushort4*>(out)[i] = o;
}

// ---------------------------------------------------------------------------
// Bucket pipeline: 782 buckets of 128 rows each (bucket = dst>>7)
// ---------------------------------------------------------------------------
__global__ __launch_bounds__(256) void bucket_hist(
    const int* __restrict__ dst, int* __restrict__ bcnt, int E)
{
    __shared__ int h[1024];
    int t = threadIdx.x;
    int lo = blockIdx.x * BINCH, hi = min(E, lo + BINCH);
    for (int i = t; i < 1024; i += 256) h[i] = 0;
    __syncthreads();
    for (int i = lo + t; i < hi; i += 256) atomicAdd(&h[dst[i] >> 7], 1);
    __syncthreads();
    for (int i = t; i < 1024; i += 256) if (h[i]) atomicAdd(&bcnt[i], h[i]);
}

__global__ __launch_bounds__(1024) void bucket_scan(
    const int* __restrict__ bcnt, int* __restrict__ bbase,
    int* __restrict__ btail, int* __restrict__ rowptr)
{
    __shared__ int s[1024];
    int t = threadIdx.x;
    int v = (t < NBK) ? bcnt[t] : 0;
    s[t] = v;
    __syncthreads();
    for (int off = 1; off < 1024; off <<= 1) {
        int u = (t >= off) ? s[t - off] : 0;
        __syncthreads();
        s[t] += u;
        __syncthreads();
    }
    int excl = s[t] - v;
    if (t < NBK) { bbase[t] = excl; btail[t] = excl; }
    if (t == NBK - 1) bbase[NBK] = excl + v;
    if (t == 0) rowptr[NN] = EE;
}

// each block: local hist of its 8192 edges, reserve contiguous runs per
// bucket via one atomicAdd each, then write uint2 records. All bytes of a
// run's cache lines come from this block (one XCD) -> L2 write-merge.
__global__ __launch_bounds__(256) void bucket_bin(
    const int* __restrict__ src, const int* __restrict__ dst,
    const float* __restrict__ val, int* __restrict__ btail,
    uint2* __restrict__ brec, int E)
{
    __shared__ int h[1024];
    __shared__ int base[1024];
    int t = threadIdx.x;
    int lo = blockIdx.x * BINCH, hi = min(E, lo + BINCH);
    for (int i = t; i < 1024; i += 256) h[i] = 0;
    __syncthreads();
    for (int i = lo + t; i < hi; i += 256) atomicAdd(&h[dst[i] >> 7], 1);
    __syncthreads();
    for (int i = t; i < 1024; i += 256) {
        int c = h[i];
        base[i] = c ? atomicAdd(&btail[i], c) : 0;
        h[i] = 0;                       // reuse as local rank counter
    }
    __syncthreads();
    for (int i = lo + t; i < hi; i += 256) {
        int d = dst[i];
        int b = d >> 7;
        int r = atomicAdd(&h[b], 1);
        uint key = ((uint)(d & 127) << 17) | (uint)src[i];
        brec[base[b] + r] = make_uint2(key, __float_as_uint(val[i]));
    }
}

// one block per bucket: row-local hist+scan -> rowptr, then write final
// dst-sorted 4B records (src<<15 | val_q15) into the bucket's epk region.
__global__ __launch_bounds__(256) void bucket_csr(
    const uint2* __restrict__ brec, const int* __restrict__ bbase,
    uint* __restrict__ epk, int* __restrict__ rowptr, int n)
{
    __shared__ int rh[128], rb[128], sc[128];
    int b = blockIdx.x;
    int t = threadIdx.x;
    int seg0 = bbase[b], seg1 = bbase[b + 1];
    int row0 = b * 128;
    if (t < 128) rh[t] = 0;
    __syncthreads();
    for (int i = seg0 + t; i < seg1; i += 256)
        atomicAdd(&rh[brec[i].x >> 17], 1);
    __syncthreads();
    if (t < 128) sc[t] = rh[t];
    __syncthreads();
    for (int off = 1; off < 128; off <<= 1) {
        int u = (t < 128 && t >= off) ? sc[t - off] : 0;
        __syncthreads();
        if (t < 128) sc[t] += u;
        __syncthreads();
    }
    if (t < 128) {
        rb[t] = sc[t] - rh[t];          // exclusive, bucket-local
        rh[t] = 0;                      // reuse as tail counter
        int row = row0 + t;
        if (row < n) rowptr[row] = seg0 + rb[t];
    }
    __syncthreads();
    for (int i = seg0 + t; i < seg1; i += 256) {
        uint2 rec = brec[i];
        uint r = rec.x >> 17;
        int p = atomicAdd(&rh[r], 1);
        float v = __uint_as_float(rec.y);
        uint vq = (uint)(v * 32767.f + 0.5f);
        epk[seg0 + rb[r] + p] = ((rec.x & 0x1ffffu) << 15) | vq;
    }
}

// ---------------------------------------------------------------------------
// SpMM-CSR bf16 -> bf16: out[i,:] = sum val * H[src,:]  (fp32 accum)
// ---------------------------------------------------------------------------
__global__ __launch_bounds__(256) void spmm_bf(
    const ushort* __restrict__ H, const int* __restrict__ rowptr,
    const uint* __restrict__ epk, ushort* __restrict__ out, int n)
{
    int w = (blockIdx.x * 256 + threadIdx.x) >> 6;
    if (w >= n) return;
    int lane = threadIdx.x & 63;
    int beg = rowptr[w];
    int end = rowptr[w + 1];
    const float sc = 1.0f / 32767.f;
    float accx = 0.f, accy = 0.f;
    int e = beg;
    for (; e + 4 <= end; e += 4) {
        uint u0 = epk[e + 0], u1 = epk[e + 1], u2 = epk[e + 2], u3 = epk[e + 3];
        uint h0 = *reinterpret_cast<const uint*>(&H[(size_t)(u0 >> 15) * DD + lane * 2]);
        uint h1 = *reinterpret_cast<const uint*>(&H[(size_t)(u1 >> 15) * DD + lane * 2]);
        uint h2 = *reinterpret_cast<const uint*>(&H[(size_t)(u2 >> 15) * DD + lane * 2]);
        uint h3 = *reinterpret_cast<const uint*>(&H[(size_t)(u3 >> 15) * DD + lane * 2]);
        float v0 = (float)(u0 & 0x7fffu) * sc;
        float v1 = (float)(u1 & 0x7fffu) * sc;
        float v2 = (float)(u2 & 0x7fffu) * sc;
        float v3 = (float)(u3 & 0x7fffu) * sc;
        accx = fmaf(v0, bf_lo(h0), accx); accy = fmaf(v0, bf_hi(h0), accy);
        accx = fmaf(v1, bf_lo(h1), accx); accy = fmaf(v1, bf_hi(h1), accy);
        accx = fmaf(v2, bf_lo(h2), accx); accy = fmaf(v2, bf_hi(h2), accy);
        accx = fmaf(v3, bf_lo(h3), accx); accy = fmaf(v3, bf_hi(h3), accy);
    }
    for (; e < end; ++e) {
        uint u0 = epk[e];
        uint h0 = *reinterpret_cast<const uint*>(&H[(size_t)(u0 >> 15) * DD + lane * 2]);
        float v0 = (float)(u0 & 0x7fffu) * sc;
        accx = fmaf(v0, bf_lo(h0), accx); accy = fmaf(v0, bf_hi(h0), accy);
    }
    uint o = ((uint)f2bf(accy) << 16) | (uint)f2bf(accx);
    *reinterpret_cast<uint*>(&out[(size_t)w * DD + lane * 2]) = o;
}

// ---------------------------------------------------------------------------
// W [128][128] fp32 row-major -> bf16 MFMA B-fragment layout
// ---------------------------------------------------------------------------
__global__ __launch_bounds__(256) void prep_w(
    const float* __restrict__ W, ushort* __restrict__ Wp)
{
    int idx = blockIdx.x * 256 + threadIdx.x;   // 16384 total
    int j  = idx & 7;
    int l  = (idx >> 3) & 63;
    int ct = (idx >> 9) & 7;
    int kk = idx >> 12;
    int k = kk * 32 + (l >> 4) * 8 + j;
    int c = ct * 16 + (l & 15);
    Wp[idx] = f2bf(W[k * DD + c]);
}

// ---------------------------------------------------------------------------
// O = bf16(relu(A @ W + b))  via mfma_f32_16x16x32_bf16
// ---------------------------------------------------------------------------
__global__ __launch_bounds__(256) void linear_mfma_relu(
    const ushort* __restrict__ A, const ushort* __restrict__ Wp,
    const float* __restrict__ bias, ushort* __restrict__ O, int n)
{
    const int wv = threadIdx.x >> 6;
    const int l  = threadIdx.x & 63;
    const int row0 = blockIdx.x * 64 + wv * 16;
    const int m = l & 15, g = l >> 4;

    f32x4 acc[8];
#pragma unroll
    for (int ct = 0; ct < 8; ++ct) acc[ct] = (f32x4){0.f, 0.f, 0.f, 0.f};

#pragma unroll
    for (int kk = 0; kk < 4; ++kk) {
        bf16x8 a = *reinterpret_cast<const bf16x8*>(
            &A[(size_t)(row0 + m) * DD + kk * 32 + g * 8]);
#pragma unroll
        for (int ct = 0; ct < 8; ++ct) {
            bf16x8 b = *reinterpret_cast<const bf16x8*>(&Wp[((kk * 8 + ct) * 64 + l) * 8]);
            acc[ct] = __builtin_amdgcn_mfma_f32_16x16x32_bf16(a, b, acc[ct], 0, 0, 0);
        }
    }
#pragma unroll
    for (int ct = 0; ct < 8; ++ct) {
        int c = ct * 16 + m;
        float bb = bias[c];
#pragma unroll
        for (int r = 0; r < 4; ++r) {
            int row = row0 + g * 4 + r;
            if (row < n)
                O[(size_t)row * DD + c] = f2bf(fmaxf(acc[ct][r] + bb, 0.f));
        }
    }
}

// ---------------------------------------------------------------------------
// out[row] = relu(A @ W + b) . Wout + bout   (layer-2 linear + head, fused)
// ---------------------------------------------------------------------------
__global__ __launch_bounds__(256) void linear_mfma_dot(
    const ushort* __restrict__ A, const ushort* __restrict__ Wp,
    const float* __restrict__ bias, const float* __restrict__ Wout,
    const float* __restrict__ bout, float* __restrict__ out, int n)
{
    const int wv = threadIdx.x >> 6;
    const int l  = threadIdx.x & 63;
    const int row0 = blockIdx.x * 64 + wv * 16;
    const int m = l & 15, g = l >> 4;

    f32x4 acc[8];
#pragma unroll
    for (int ct = 0; ct < 8; ++ct) acc[ct] = (f32x4){0.f, 0.f, 0.f, 0.f};

#pragma unroll
    for (int kk = 0; kk < 4; ++kk) {
        bf16x8 a = *reinterpret_cast<const bf16x8*>(
            &A[(size_t)(row0 + m) * DD + kk * 32 + g * 8]);
#pragma unroll
        for (int ct = 0; ct < 8; ++ct) {
            bf16x8 b = *reinterpret_cast<const bf16x8*>(&Wp[((kk * 8 + ct) * 64 + l) * 8]);
            acc[ct] = __builtin_amdgcn_mfma_f32_16x16x32_bf16(a, b, acc[ct], 0, 0, 0);
        }
    }
    float srow[4] = {0.f, 0.f, 0.f, 0.f};
#pragma unroll
    for (int ct = 0; ct < 8; ++ct) {
        int c = ct * 16 + m;
        float bb = bias[c];
        float wo = Wout[c];
#pragma unroll
        for (int r = 0; r < 4; ++r)
            srow[r] = fmaf(fmaxf(acc[ct][r] + bb, 0.f), wo, srow[r]);
    }
#pragma unroll
    for (int r = 0; r < 4; ++r) {
        float s = srow[r];
        s += __shfl_xor(s, 1, 64);
        s += __shfl_xor(s, 2, 64);
        s += __shfl_xor(s, 4, 64);
        s += __shfl_xor(s, 8, 64);
        srow[r] = s;
    }
    if (m == 0) {
        float bo = bout[0];
#pragma unroll
        for (int r = 0; r < 4; ++r) {
            int row = row0 + g * 4 + r;
            if (row < n) out[row] = srow[r] + bo;
        }
    }
}

extern "C" void kernel_launch(void* const* d_in, const int* in_sizes, int n_in,
                              void* d_out, int out_size, void* d_ws, size_t ws_size,
                              hipStream_t stream)
{
    const float* x    = (const float*)d_in[0];
    const int*   esrc = (const int*)  d_in[1];
    const int*   edst = (const int*)  d_in[2];
    const float* eval = (const float*)d_in[3];
    const float* W1   = (const float*)d_in[4];
    const float* b1   = (const float*)d_in[5];
    const float* W2   = (const float*)d_in[6];
    const float* b2   = (const float*)d_in[7];
    const float* Wout = (const float*)d_in[8];
    const float* bout = (const float*)d_in[9];
    float* out = (float*)d_out;

    // workspace layout
    ushort* w1p    = (ushort*)d_ws;                      // 16384
    ushort* w2p    = w1p + 16384;                        // 16384
    ushort* hbf    = w2p + 16384;                        // [N][128] bf16 x
    ushort* bufS   = hbf + (size_t)NN * DD;              // [N][128] bf16 spmm out
    ushort* bufL   = bufS + (size_t)NN * DD;             // [N][128] bf16 linear out
    uint*   epk    = (uint*)(bufL + (size_t)NN * DD);    // [E] final packed records
    uint2*  brec   = (uint2*)(epk + EE);                 // [E] bucket records
    int*    bcnt   = (int*)(brec + EE);                  // [1024]
    int*    bbase  = bcnt + 1024;                        // [NBK+1]
    int*    btail  = bbase + (NBK + 1);                  // [NBK]
    int*    rowptr = btail + NBK;                        // [N+1]

    const int spmmGrid = (NN * 64 + 255) / 256;
    const int linGrid  = (NN + 63) / 64;
    const int castGrid = (NN * DD / 4 + 255) / 256;

    // --- build dst-sorted edge structure (bucketed counting sort) ---
    hipMemsetAsync(bcnt, 0, 1024 * sizeof(int), stream);
    cast_bf16<<<castGrid, 256, 0, stream>>>(x, hbf, NN * DD / 4);
    prep_w<<<64, 256, 0, stream>>>(W1, w1p);
    prep_w<<<64, 256, 0, stream>>>(W2, w2p);
    bucket_hist<<<BINGRID, 256, 0, stream>>>(edst, bcnt, EE);
    bucket_scan<<<1, 1024, 0, stream>>>(bcnt, bbase, btail, rowptr);
    bucket_bin<<<BINGRID, 256, 0, stream>>>(esrc, edst, eval, btail, brec, EE);
    bucket_csr<<<NBK, 256, 0, stream>>>(brec, bbase, epk, rowptr, NN);

    // --- layer 1 ---
    spmm_bf<<<spmmGrid, 256, 0, stream>>>(hbf, rowptr, epk, bufS, NN);
    linear_mfma_relu<<<linGrid, 256, 0, stream>>>(bufS, w1p, b1, bufL, NN);
    // --- layer 2 ---
    spmm_bf<<<spmmGrid, 256, 0, stream>>>(bufL, rowptr, epk, bufS, NN);
    linear_mfma_dot<<<linGrid, 256, 0, stream>>>(bufS, w2p, b2, Wout, bout, out, NN);
}